// Round 3
// baseline (669.704 us; speedup 1.0000x reference)
//
#include <hip/hip_runtime.h>
#include <hip/hip_bf16.h>

typedef _Float16 f16;
typedef _Float16 f16x8 __attribute__((ext_vector_type(8)));
typedef float    f32x4 __attribute__((ext_vector_type(4)));

#define HDIM 128
#define IDIM 4
#define TLEN 512
#define GDIM 512   // 4*H

__device__ __forceinline__ float sigm(float x){
  return 1.0f / (1.0f + __expf(-x));
}
__device__ __forceinline__ float tanh_fast(float x){
  float t = fabsf(x);
  float e = __expf(-2.0f * t);
  float r = (1.0f - e) / (1.0f + e);
  return copysignf(r, x);
}

// One block = one direction x two batch chains (M=2 padded to 16 for MFMA).
// Wave w owns gate-column tiles {w, w+8, w+16, w+24} -> all 4 gates of hidden
// j = w*16 + lane live in lane (lane<16), regs 0/1 = chains 0/1. Whh resident
// as 16 f16 B-fragments (64 VGPRs). One barrier per step; xw and h double-buffered.
__global__ __launch_bounds__(512, 2) void bilstm_mfma(
    const float* __restrict__ x,
    const float* __restrict__ Wih_f, const float* __restrict__ Whh_f,
    const float* __restrict__ bih_f, const float* __restrict__ bhh_f,
    const float* __restrict__ Wih_b, const float* __restrict__ Whh_b,
    const float* __restrict__ bih_b, const float* __restrict__ bhh_b,
    float* __restrict__ out)
{
  __shared__ float xs[2][TLEN*IDIM];            // 16 KB: x for both chains
  __shared__ float xw[2][GDIM][2];              //  8 KB: input proj, double-buffered
  __shared__ __align__(16) f16 hl[2][2][HDIM];  //  1 KB: h (f16), double-buffered

  const int tid = threadIdx.x;
  const int w   = tid >> 6;        // wave 0..7
  const int l   = tid & 63;        // lane
  const int dir = blockIdx.x >> 7; // 0 fwd, 1 bwd
  const int b0  = (blockIdx.x & 127) * 2;

  const float* Wih = dir ? Wih_b : Wih_f;
  const float* Whh = dir ? Whh_b : Whh_f;
  const float* bih = dir ? bih_b : bih_f;
  const float* bhh = dir ? bhh_b : bhh_f;

  // ---- one-time: B fragments (Whh^T), 4 gate-tiles x 4 K-frags ----
  // B[k][n]: lane holds n = l&15, k = ks*32 + (l>>4)*8 + e (e=0..7).
  // tile t -> gate col g_n = t*128 + w*16 + (l&15).
  f16x8 bfrag[4][4];
  {
    const int n = (l & 15);
    #pragma unroll
    for (int t = 0; t < 4; ++t){
      const int gn = t*128 + w*16 + n;
      #pragma unroll
      for (int ks = 0; ks < 4; ++ks){
        const float* p = Whh + gn*HDIM + ks*32 + (l>>4)*8;
        float4 qa = ((const float4*)p)[0];
        float4 qb = ((const float4*)p)[1];
        f16x8 v = { (f16)qa.x,(f16)qa.y,(f16)qa.z,(f16)qa.w,
                    (f16)qb.x,(f16)qb.y,(f16)qb.z,(f16)qb.w };
        bfrag[t][ks] = v;
      }
    }
  }

  // ---- per-thread input-projection row (g = tid) ----
  const float4 wiv = *(const float4*)(Wih + tid*IDIM);
  const float bias = bih[tid] + bhh[tid];

  // ---- stage x (coalesced float4) ----
  {
    const float4* src0 = (const float4*)(x + (size_t)(b0+0)*TLEN*IDIM);
    const float4* src1 = (const float4*)(x + (size_t)(b0+1)*TLEN*IDIM);
    ((float4*)xs[0])[tid] = src0[tid];
    ((float4*)xs[1])[tid] = src1[tid];
  }
  // h_0 = 0
  if (tid < 2*HDIM) hl[0][tid>>7][tid & (HDIM-1)] = (f16)0.0f;
  // xw for step 0
  {
    const int tt = dir ? (TLEN-1) : 0;
    const float4 xv0 = ((const float4*)xs[0])[tt];
    const float4 xv1 = ((const float4*)xs[1])[tt];
    float a0 = bias + wiv.x*xv0.x + wiv.y*xv0.y + wiv.z*xv0.z + wiv.w*xv0.w;
    float a1 = bias + wiv.x*xv1.x + wiv.y*xv1.y + wiv.z*xv1.z + wiv.w*xv1.w;
    xw[0][tid][0] = a0;
    xw[0][tid][1] = a1;
  }
  __syncthreads();

  float c0 = 0.f, c1 = 0.f, h0o = 0.f, h1o = 0.f;  // live in lanes l<16
  const int row = l & 15;
  const int jcol = w*16 + row;                     // hidden index owned (l<16)

  for (int s = 0; s < TLEN; ++s){
    const int rb = s & 1, wb = (s + 1) & 1;

    // A fragments from h (rows 0,1 real, rest zero)
    f16x8 a[4];
    #pragma unroll
    for (int ks = 0; ks < 4; ++ks){
      if (row < 2) a[ks] = *(const f16x8*)&hl[rb][row][ks*32 + (l>>4)*8];
      else         a[ks] = (f16x8)(f16)0.0f;
    }

    // C init = xw (rows 0,1 at lanes<16, regs 0,1) — verified C layout
    f32x4 acc[4];
    #pragma unroll
    for (int t = 0; t < 4; ++t){
      f32x4 z = {0.f, 0.f, 0.f, 0.f};
      if (l < 16){
        float2 p = *(const float2*)&xw[rb][t*128 + jcol][0];
        z.x = p.x; z.y = p.y;
      }
      acc[t] = z;
    }

    // 16 MFMA: 4 gate tiles x K=128
    #pragma unroll
    for (int t = 0; t < 4; ++t)
      #pragma unroll
      for (int ks = 0; ks < 4; ++ks)
        acc[t] = __builtin_amdgcn_mfma_f32_16x16x32_f16(a[ks], bfrag[t][ks], acc[t], 0, 0, 0);

    // activation + c/h update, lane-local (l<16)
    if (l < 16){
      float iv0 = sigm(acc[0].x), iv1 = sigm(acc[0].y);
      float fv0 = sigm(acc[1].x), fv1 = sigm(acc[1].y);
      float gv0 = tanh_fast(acc[2].x), gv1 = tanh_fast(acc[2].y);
      float ov0 = sigm(acc[3].x), ov1 = sigm(acc[3].y);
      c0 = fv0*c0 + iv0*gv0;
      c1 = fv1*c1 + iv1*gv1;
      h0o = ov0 * tanh_fast(c0);
      h1o = ov1 * tanh_fast(c1);
      hl[wb][0][jcol] = (f16)h0o;
      hl[wb][1][jcol] = (f16)h1o;
    }

    // input projection for step s+1 (all threads; double-buffered)
    if (s + 1 < TLEN){
      const int tt = dir ? (TLEN-1-(s+1)) : (s+1);
      const float4 xv0 = ((const float4*)xs[0])[tt];
      const float4 xv1 = ((const float4*)xs[1])[tt];
      float a0 = bias + wiv.x*xv0.x + wiv.y*xv0.y + wiv.z*xv0.z + wiv.w*xv0.w;
      float a1 = bias + wiv.x*xv1.x + wiv.y*xv1.y + wiv.z*xv1.z + wiv.w*xv1.w;
      xw[wb][tid][0] = a0;
      xw[wb][tid][1] = a1;
    }
    __syncthreads();
  }

  // final h_T -> out[b, dir*128 + j]
  if (l < 16){
    out[(size_t)(b0+0)*(2*HDIM) + dir*HDIM + jcol] = h0o;
    out[(size_t)(b0+1)*(2*HDIM) + dir*HDIM + jcol] = h1o;
  }
}

extern "C" void kernel_launch(void* const* d_in, const int* in_sizes, int n_in,
                              void* d_out, int out_size, void* d_ws, size_t ws_size,
                              hipStream_t stream)
{
  const float* x     = (const float*)d_in[0];
  const float* Wih_f = (const float*)d_in[1];
  const float* Whh_f = (const float*)d_in[2];
  const float* bih_f = (const float*)d_in[3];
  const float* bhh_f = (const float*)d_in[4];
  const float* Wih_b = (const float*)d_in[5];
  const float* Whh_b = (const float*)d_in[6];
  const float* bih_b = (const float*)d_in[7];
  const float* bhh_b = (const float*)d_in[8];

  bilstm_mfma<<<dim3(256), dim3(512), 0, stream>>>(
      x, Wih_f, Whh_f, bih_f, bhh_f, Wih_b, Whh_b, bih_b, bhh_b,
      (float*)d_out);
}

// Round 4
// 473.853 us; speedup vs baseline: 1.4133x; 1.4133x over previous
//
#include <hip/hip_runtime.h>
#include <hip/hip_bf16.h>

typedef _Float16 f16;
typedef _Float16 f16x8 __attribute__((ext_vector_type(8)));
typedef float    f32x4 __attribute__((ext_vector_type(4)));

#define HDIM 128
#define IDIM 4
#define TLEN 512

__device__ __forceinline__ float sigm(float x){
  return 1.0f / (1.0f + __expf(-x));
}
__device__ __forceinline__ float tanh_fast(float x){
  float t = fabsf(x);
  float e = __expf(-2.0f * t);
  float r = (1.0f - e) / (1.0f + e);
  return copysignf(r, x);
}

// Block = 1 direction x 2 batch chains. 8 waves; wave w owns gate-cols
// {w,w+8,w+16,w+24}*16 so all 4 gates of hidden j=w*16+c are lane-local.
// h is exchanged through LDS pre-formatted in MFMA A-fragment layout
// (rows>=2 permanently zero) -> unpredicated conflict-free b128 loads.
// Whh lives in 64 VGPRs per wave (pinned via empty asm to avoid AGPR homes).
__global__ __launch_bounds__(512, 2) void bilstm_mfma2(
    const float* __restrict__ x,
    const float* __restrict__ Wih_f, const float* __restrict__ Whh_f,
    const float* __restrict__ bih_f, const float* __restrict__ bhh_f,
    const float* __restrict__ Wih_b, const float* __restrict__ Whh_b,
    const float* __restrict__ bih_b, const float* __restrict__ bhh_b,
    float* __restrict__ out)
{
  __shared__ float xs[2][TLEN*IDIM];              // 16 KB staged x (2 chains)
  __shared__ float xw[2][4*HDIM][2];              //  8 KB input-proj, dbuf
  __shared__ __align__(16) f16 ha[2][4][64][8];   //  8 KB h in A-frag layout, dbuf

  const int tid = threadIdx.x;
  const int w   = tid >> 6;        // wave 0..7
  const int l   = tid & 63;        // lane
  const int c16 = l & 15;
  const int dir = blockIdx.x >> 7; // 0 fwd, 1 bwd
  const int b0  = (blockIdx.x & 127) * 2;

  const float* Wih = dir ? Wih_b : Wih_f;
  const float* Whh = dir ? Whh_b : Whh_f;
  const float* bih = dir ? bih_b : bih_f;
  const float* bhh = dir ? bhh_b : bhh_f;

  // ---- one-time: B fragments (Whh^T): B[k][n], n = c16, k = ks*32+(l>>4)*8+e ----
  f16x8 bfrag[4][4];
  #pragma unroll
  for (int t = 0; t < 4; ++t){
    const int gn = t*128 + w*16 + c16;
    #pragma unroll
    for (int ks = 0; ks < 4; ++ks){
      const float* p = Whh + gn*HDIM + ks*32 + (l>>4)*8;
      float4 qa = ((const float4*)p)[0];
      float4 qb = ((const float4*)p)[1];
      f16x8 v = { (f16)qa.x,(f16)qa.y,(f16)qa.z,(f16)qa.w,
                  (f16)qb.x,(f16)qb.y,(f16)qb.z,(f16)qb.w };
      bfrag[t][ks] = v;
    }
  }
  // pin Whh fragments into VGPR homes (prevents AGPR demotion + per-use copies)
  #pragma unroll
  for (int t = 0; t < 4; ++t)
    #pragma unroll
    for (int ks = 0; ks < 4; ++ks)
      asm("" : "+v"(bfrag[t][ks]));

  // ---- per-thread input-projection row (gate g = tid) ----
  const float4 wiv = *(const float4*)(Wih + tid*IDIM);
  const float bias = bih[tid] + bhh[tid];

  // ---- stage x (coalesced), zero ha (both buffers), xw step-0 from GLOBAL x ----
  {
    const float4* src0 = (const float4*)(x + (size_t)(b0+0)*TLEN*IDIM);
    const float4* src1 = (const float4*)(x + (size_t)(b0+1)*TLEN*IDIM);
    ((float4*)xs[0])[tid] = src0[tid];
    ((float4*)xs[1])[tid] = src1[tid];
  }
  {
    int* hz = (int*)ha;          // 2*4*64*8 f16 = 2048 ints
    hz[tid] = 0; hz[tid+512] = 0; hz[tid+1024] = 0; hz[tid+1536] = 0;
  }
  {
    const int tt0 = dir ? (TLEN-1) : 0;
    float4 xv0 = *(const float4*)(x + ((size_t)(b0+0)*TLEN + tt0)*IDIM);
    float4 xv1 = *(const float4*)(x + ((size_t)(b0+1)*TLEN + tt0)*IDIM);
    xw[0][tid][0] = bias + wiv.x*xv0.x + wiv.y*xv0.y + wiv.z*xv0.z + wiv.w*xv0.w;
    xw[0][tid][1] = bias + wiv.x*xv1.x + wiv.y*xv1.y + wiv.z*xv1.z + wiv.w*xv1.w;
  }
  __syncthreads();

  float c = 0.0f, hout = 0.0f;     // chain state: lane l<32 holds (chain=l>>4, j=w*16+c16)
  const int chainbit = (l >> 4) & 1;

  for (int s = 0; s < TLEN; ++s){
    const int rb = s & 1, wb = rb ^ 1;

    // A fragments: unpredicated, conflict-free (1 KB contiguous per wave)
    f16x8 a0 = *(const f16x8*)&ha[rb][0][l][0];
    f16x8 a1 = *(const f16x8*)&ha[rb][1][l][0];
    f16x8 a2 = *(const f16x8*)&ha[rb][2][l][0];
    f16x8 a3 = *(const f16x8*)&ha[rb][3][l][0];

    // C init = {xw0, xw1, 0, 0} on ALL lanes (broadcast reads; garbage rows unread)
    f32x4 acc[4];
    #pragma unroll
    for (int t = 0; t < 4; ++t){
      float2 p = *(const float2*)&xw[rb][t*128 + w*16 + c16][0];
      f32x4 z = { p.x, p.y, 0.f, 0.f };
      acc[t] = z;
      asm("" : "+v"(acc[t]));      // keep C in arch VGPRs
    }

    // input projection for step s+1 (independent of MFMA; scheduler overlaps)
    {
      const int ttn = (dir ? (TLEN-2-s) : (s+1)) & (TLEN-1);
      const float4 xv0 = ((const float4*)xs[0])[ttn];
      const float4 xv1 = ((const float4*)xs[1])[ttn];
      float q0 = bias + wiv.x*xv0.x + wiv.y*xv0.y + wiv.z*xv0.z + wiv.w*xv0.w;
      float q1 = bias + wiv.x*xv1.x + wiv.y*xv1.y + wiv.z*xv1.z + wiv.w*xv1.w;
      xw[wb][tid][0] = q0;
      xw[wb][tid][1] = q1;
    }

    // 16 MFMA: 4 gate tiles x K=128
    #pragma unroll
    for (int t = 0; t < 4; ++t){
      acc[t] = __builtin_amdgcn_mfma_f32_16x16x32_f16(a0, bfrag[t][0], acc[t], 0, 0, 0);
      acc[t] = __builtin_amdgcn_mfma_f32_16x16x32_f16(a1, bfrag[t][1], acc[t], 0, 0, 0);
      acc[t] = __builtin_amdgcn_mfma_f32_16x16x32_f16(a2, bfrag[t][2], acc[t], 0, 0, 0);
      acc[t] = __builtin_amdgcn_mfma_f32_16x16x32_f16(a3, bfrag[t][3], acc[t], 0, 0, 0);
      asm("" : "+v"(acc[t]));      // keep D in arch VGPRs
    }

    // spread chain1 (reg .y, lanes 0-15) to lanes 16-31; unpredicated activation
    float val[4];
    #pragma unroll
    for (int t = 0; t < 4; ++t){
      int pv = __builtin_amdgcn_ds_bpermute(c16 << 2, __float_as_int(acc[t].y));
      val[t] = chainbit ? __int_as_float(pv) : acc[t].x;
    }
    float iv = sigm(val[0]);
    float fv = sigm(val[1]);
    float gv = tanh_fast(val[2]);
    float ov = sigm(val[3]);
    c    = fv*c + iv*gv;
    hout = ov * tanh_fast(c);

    // h -> ha[wb] in A-frag layout: k=j=w*16+c16 (ks=w>>1), row m=l>>4
    if (l < 32){
      const int G = (l >> 4) + ((2*w + (c16 >> 3)) & 3) * 16;
      ha[wb][w>>1][G][c16 & 7] = (f16)hout;
    }
    __syncthreads();
  }

  // final h_T -> out[b, dir*128 + j]
  if (l < 32){
    out[(size_t)(b0 + (l>>4))*(2*HDIM) + dir*HDIM + w*16 + c16] = hout;
  }
}

extern "C" void kernel_launch(void* const* d_in, const int* in_sizes, int n_in,
                              void* d_out, int out_size, void* d_ws, size_t ws_size,
                              hipStream_t stream)
{
  const float* x     = (const float*)d_in[0];
  const float* Wih_f = (const float*)d_in[1];
  const float* Whh_f = (const float*)d_in[2];
  const float* bih_f = (const float*)d_in[3];
  const float* bhh_f = (const float*)d_in[4];
  const float* Wih_b = (const float*)d_in[5];
  const float* Whh_b = (const float*)d_in[6];
  const float* bih_b = (const float*)d_in[7];
  const float* bhh_b = (const float*)d_in[8];

  bilstm_mfma2<<<dim3(256), dim3(512), 0, stream>>>(
      x, Wih_f, Whh_f, bih_f, bhh_f, Wih_b, Whh_b, bih_b, bhh_b,
      (float*)d_out);
}

// Round 6
// 437.088 us; speedup vs baseline: 1.5322x; 1.0841x over previous
//
#include <hip/hip_runtime.h>
#include <hip/hip_bf16.h>

typedef _Float16 f16;
typedef _Float16 f16x8 __attribute__((ext_vector_type(8)));
typedef _Float16 f16x4 __attribute__((ext_vector_type(4)));
typedef float    f32x4 __attribute__((ext_vector_type(4)));

#define HDIM 128
#define IDIM 4
#define TLEN 512

__device__ __forceinline__ float sigm(float x){
  return 1.0f / (1.0f + __expf(-x));           // add, exp(mul+trans), rcp
}
__device__ __forceinline__ float tanh_fast(float x){
  return 1.0f - 2.0f / (1.0f + __expf(2.0f*x)); // mul, exp, add, rcp, fma
}

// Block = 1 direction x 2 batch chains. 8 waves; wave w owns gate-cols
// {w,w+8,w+16,w+24}*16. K-extended MFMA: gates = [h | x_t | 1] @ [Whh^T; Wih^T; bias]
// (K=160, 5 K-frags) -> no xw pipeline, C-init is literal zero.
// h exchanged via LDS in A-fragment layout (rows>=2 permanently zero).
__global__ __launch_bounds__(512, 2) void bilstm_mfma3(
    const float* __restrict__ x,
    const float* __restrict__ Wih_f, const float* __restrict__ Whh_f,
    const float* __restrict__ bih_f, const float* __restrict__ bhh_f,
    const float* __restrict__ Wih_b, const float* __restrict__ Whh_b,
    const float* __restrict__ bih_b, const float* __restrict__ bhh_b,
    float* __restrict__ out)
{
  __shared__ __align__(16) f16 xs16[2][TLEN][IDIM];  // 8 KB: x (f16), both chains
  __shared__ __align__(16) f16 ha[2][4][64][8];      // 8 KB: h in A-frag layout, dbuf

  const int tid = threadIdx.x;
  const int w   = tid >> 6;        // wave 0..7
  const int l   = tid & 63;        // lane
  const int c16 = l & 15;
  const int dir = blockIdx.x >> 7; // 0 fwd, 1 bwd
  const int b0  = (blockIdx.x & 127) * 2;

  const float* Wih = dir ? Wih_b : Wih_f;
  const float* Whh = dir ? Whh_b : Whh_f;
  const float* bih = dir ? bih_b : bih_f;
  const float* bhh = dir ? bhh_b : bhh_f;

  // ---- one-time: B fragments. Main K=128 from Whh^T; ext frag ks=4 holds
  // rows k=128..132 = [Wih^T ; bias] (lanes l<16 only; rest zero via A). ----
  f16x8 bfrag[4][5];
  #pragma unroll
  for (int t = 0; t < 4; ++t){
    const int gn = t*128 + w*16 + c16;
    #pragma unroll
    for (int ks = 0; ks < 4; ++ks){
      const float* p = Whh + gn*HDIM + ks*32 + (l>>4)*8;
      float4 qa = ((const float4*)p)[0];
      float4 qb = ((const float4*)p)[1];
      f16x8 v = { (f16)qa.x,(f16)qa.y,(f16)qa.z,(f16)qa.w,
                  (f16)qb.x,(f16)qb.y,(f16)qb.z,(f16)qb.w };
      bfrag[t][ks] = v;
    }
    f16x8 v4 = (f16x8)(f16)0.0f;
    if (l < 16){
      const float4 wq = *(const float4*)(Wih + gn*IDIM);
      const float bb = bih[gn] + bhh[gn];
      v4[0] = (f16)wq.x; v4[1] = (f16)wq.y;
      v4[2] = (f16)wq.z; v4[3] = (f16)wq.w;
      v4[4] = (f16)bb;
    }
    bfrag[t][4] = v4;
  }
  #pragma unroll
  for (int t = 0; t < 4; ++t)
    #pragma unroll
    for (int ks = 0; ks < 5; ++ks)
      asm("" : "+v"(bfrag[t][ks]));

  // ---- stage x as f16 (coalesced float4 reads), zero ha ----
  {
    const float4* src0 = (const float4*)(x + (size_t)(b0+0)*TLEN*IDIM);
    const float4* src1 = (const float4*)(x + (size_t)(b0+1)*TLEN*IDIM);
    float4 v0 = src0[tid], v1 = src1[tid];
    f16x4 h0 = { (f16)v0.x, (f16)v0.y, (f16)v0.z, (f16)v0.w };
    f16x4 h1 = { (f16)v1.x, (f16)v1.y, (f16)v1.z, (f16)v1.w };
    *(f16x4*)&xs16[0][tid][0] = h0;
    *(f16x4*)&xs16[1][tid][0] = h1;
  }
  {
    int* hz = (int*)ha;          // 2*4*64*8 f16 = 2048 ints
    hz[tid] = 0; hz[tid+512] = 0; hz[tid+1024] = 0; hz[tid+1536] = 0;
  }
  __syncthreads();

  float c = 0.0f, hout = 0.0f;   // lanes l<32: (chain=l>>4, j=w*16+c16)
  const int chainbit = (l >> 4) & 1;
  int tt = dir ? (TLEN-1) : 0;
  const int dt = dir ? -1 : 1;

  const int Gw  = (l >> 4) + ((2*w + (c16 >> 3)) & 3) * 16;  // ha write lane
  const int kse = w >> 1;                                    // ha write ks
  const int ew  = c16 & 7;                                   // ha write elem

#define STEP(RB, WB)                                                          \
  {                                                                           \
    f16x8 a0 = *(const f16x8*)&ha[RB][0][l][0];                               \
    f16x8 a1 = *(const f16x8*)&ha[RB][1][l][0];                               \
    f16x8 a2 = *(const f16x8*)&ha[RB][2][l][0];                               \
    f16x8 a3 = *(const f16x8*)&ha[RB][3][l][0];                               \
    f16x4 xq0 = *(const f16x4*)&xs16[0][tt][0];                               \
    f16x4 xq1 = *(const f16x4*)&xs16[1][tt][0];                               \
    f16x4 zq  = (f16x4)(f16)0.0f;                                             \
    f16x4 sel = (l == 0) ? xq0 : ((l == 1) ? xq1 : zq);                       \
    f16x8 a4  = (f16x8)(f16)0.0f;                                             \
    a4[0] = sel[0]; a4[1] = sel[1]; a4[2] = sel[2]; a4[3] = sel[3];           \
    a4[4] = (l < 2) ? (f16)1.0f : (f16)0.0f;                                  \
    f32x4 zero4 = { 0.f, 0.f, 0.f, 0.f };                                     \
    f32x4 acc[4];                                                             \
    _Pragma("unroll")                                                         \
    for (int t = 0; t < 4; ++t){                                              \
      acc[t] = __builtin_amdgcn_mfma_f32_16x16x32_f16(a0, bfrag[t][0], zero4, 0,0,0); \
      acc[t] = __builtin_amdgcn_mfma_f32_16x16x32_f16(a1, bfrag[t][1], acc[t], 0,0,0); \
      acc[t] = __builtin_amdgcn_mfma_f32_16x16x32_f16(a2, bfrag[t][2], acc[t], 0,0,0); \
      acc[t] = __builtin_amdgcn_mfma_f32_16x16x32_f16(a3, bfrag[t][3], acc[t], 0,0,0); \
      acc[t] = __builtin_amdgcn_mfma_f32_16x16x32_f16(a4, bfrag[t][4], acc[t], 0,0,0); \
    }                                                                         \
    float val[4];                                                             \
    _Pragma("unroll")                                                         \
    for (int t = 0; t < 4; ++t){                                              \
      int pv = __builtin_amdgcn_ds_bpermute(c16 << 2, __float_as_int(acc[t].y)); \
      val[t] = chainbit ? __int_as_float(pv) : acc[t].x;                      \
    }                                                                         \
    float iv = sigm(val[0]);                                                  \
    float fv = sigm(val[1]);                                                  \
    float gv = tanh_fast(val[2]);                                             \
    float ov = sigm(val[3]);                                                  \
    c    = fv*c + iv*gv;                                                      \
    hout = ov * tanh_fast(c);                                                 \
    if (l < 32) ha[WB][kse][Gw][ew] = (f16)hout;                              \
    tt += dt;                                                                 \
    __syncthreads();                                                          \
  }

  for (int s = 0; s < TLEN; s += 2){
    STEP(0, 1)
    STEP(1, 0)
  }
#undef STEP

  // final h_T -> out[b, dir*128 + j]
  if (l < 32){
    out[(size_t)(b0 + (l>>4))*(2*HDIM) + dir*HDIM + w*16 + c16] = hout;
  }
}

extern "C" void kernel_launch(void* const* d_in, const int* in_sizes, int n_in,
                              void* d_out, int out_size, void* d_ws, size_t ws_size,
                              hipStream_t stream)
{
  const float* x     = (const float*)d_in[0];
  const float* Wih_f = (const float*)d_in[1];
  const float* Whh_f = (const float*)d_in[2];
  const float* bih_f = (const float*)d_in[3];
  const float* bhh_f = (const float*)d_in[4];
  const float* Wih_b = (const float*)d_in[5];
  const float* Whh_b = (const float*)d_in[6];
  const float* bih_b = (const float*)d_in[7];
  const float* bhh_b = (const float*)d_in[8];

  bilstm_mfma3<<<dim3(256), dim3(512), 0, stream>>>(
      x, Wih_f, Whh_f, bih_f, bhh_f, Wih_b, Whh_b, bih_b, bhh_b,
      (float*)d_out);
}